// Round 3
// baseline (702.908 us; speedup 1.0000x reference)
//
#include <hip/hip_runtime.h>
#include <stdint.h>

typedef unsigned short u16;
typedef short v8s __attribute__((ext_vector_type(8)));
typedef float v4f __attribute__((ext_vector_type(4)));

typedef __attribute__((address_space(1))) uint32_t g_u32;
typedef __attribute__((address_space(3))) uint32_t l_u32;

// async global->LDS, 16B per lane; LDS dest = wave-uniform base + lane*16
__device__ __forceinline__ void glds16(const void* g, void* l) {
    __builtin_amdgcn_global_load_lds((const g_u32*)g, (l_u32*)l, 16, 0, 0);
}

// scalar fp32 -> bf16, round-to-nearest-even
__device__ __forceinline__ u16 f2b(float f) {
    uint32_t u = __builtin_bit_cast(uint32_t, f);
    u += 0x7FFFu + ((u >> 16) & 1u);
    return (u16)(u >> 16);
}

// pack two fp32 -> two bf16 in one u32 (round-half-up)
__device__ __forceinline__ uint32_t pk2(float a, float b) {
    uint32_t ua = __builtin_bit_cast(uint32_t, a) + 0x8000u;
    uint32_t ub = __builtin_bit_cast(uint32_t, b) + 0x8000u;
    return __builtin_amdgcn_perm(ub, ua, 0x07060302u);  // lo = ua.hi16, hi = ub.hi16
}

#define MTOT  32768
#define HDIM  768
#define KDIM  2000
#define KPAD  2016

// ---------------- K-1: convert A (fp32 -> bf16), row-major M x 2000 ---------------------
__global__ __launch_bounds__(256) void cvt_a(
    const float* __restrict__ A, u16* __restrict__ Ab)
{
    const int t = threadIdx.x;
    if (t >= 250) return;                       // 250 * 8 = 2000
#pragma unroll
    for (int r = 0; r < 8; r++) {
        const int row = blockIdx.x * 8 + r;     // grid 4096
        const float* src = A + (size_t)row * KDIM + t * 8;
        const float4 a = ((const float4*)src)[0];
        const float4 b = ((const float4*)src)[1];
        int4 p;
        p.x = (int)pk2(a.x, a.y); p.y = (int)pk2(a.z, a.w);
        p.z = (int)pk2(b.x, b.y); p.w = (int)pk2(b.z, b.w);
        *(int4*)(Ab + (size_t)row * KDIM + t * 8) = p;
    }
}

// ---------------- K0: convert weights to bf16 (proj_w padded K 2000->2016, zeros) -------
__global__ __launch_bounds__(256) void cvt_weights(
    const float* __restrict__ pw, const float* __restrict__ nw,
    u16* __restrict__ Wb, u16* __restrict__ NWb)
{
    const int h = blockIdx.x;  // 768 blocks
    const float* src = pw + (size_t)h * KDIM;
    u16* dst = Wb + (size_t)h * KPAD;
    for (int k = threadIdx.x; k < KPAD; k += 256)
        dst[k] = (k < KDIM) ? f2b(src[k]) : (u16)0;
    const float* s2 = nw + (size_t)h * HDIM;
    u16* d2 = NWb + (size_t)h * HDIM;
    for (int k = threadIdx.x; k < HDIM; k += 256)
        d2[k] = f2b(s2[k]);
}

// ---------------- K1: GEMM1 (lean m97): x = Ab . Wb^T + bias + 5 gathers ----------------
// 128x128 tile, BK=32, all-bf16, glds staging both tiles, XOR-swizzled LDS.
// K-tail: A glds source clamped to k<=1992 (in-bounds); Wb zero-padded -> extra terms 0.
__global__ __launch_bounds__(256, 4) void gemm1(
    const u16* __restrict__ Ab, const u16* __restrict__ Wb,
    const float* __restrict__ pb,
    const int* __restrict__ i_ty, const int* __restrict__ i_la,
    const int* __restrict__ i_op, const int* __restrict__ i_in, const int* __restrict__ i_ou,
    const float* __restrict__ te, const float* __restrict__ le, const float* __restrict__ oe,
    const float* __restrict__ ie, const float* __restrict__ ooe,
    u16* __restrict__ Xb)
{
    __shared__ __align__(16) u16 As[128 * 32];
    __shared__ __align__(16) u16 Bs[128 * 32];

    const int bid = blockIdx.x;            // 1536 = 256 m-tiles * 6 n-tiles
    const int slot = bid >> 3;
    const int mt = (bid & 7) * 32 + slot / 6;
    const int nt = slot % 6;
    const int m_base = mt * 128, n_base = nt * 128;

    const int tid = threadIdx.x;
    const int w = tid >> 6, lane = tid & 63;
    const int lm = lane & 15, quad = lane >> 4;
    const int wm = (w >> 1) * 64, wn = (w & 1) * 64;

    // staging: wave w covers local rows [w*32, w*32+32), 2 glds each side.
    // LDS slot s = lane&3 holds global chunk c = s ^ ((rowl>>1)&3).
    const u16* aRow[2]; int aOff[2]; u16* aDst[2];
    const u16* bSrc[2]; u16* bDst[2];
#pragma unroll
    for (int t = 0; t < 2; t++) {
        const int rl = w * 32 + t * 16 + (lane >> 2);
        const int c = (lane & 3) ^ ((rl >> 1) & 3);
        aRow[t] = Ab + (size_t)(m_base + rl) * KDIM;
        aOff[t] = c * 8;
        aDst[t] = (u16*)&As[(w * 32 + t * 16) * 32];
        bSrc[t] = Wb + (size_t)(n_base + rl) * KPAD + c * 8;
        bDst[t] = (u16*)&Bs[(w * 32 + t * 16) * 32];
    }

    v4f acc[4][4];
#pragma unroll
    for (int i = 0; i < 4; i++)
#pragma unroll
        for (int j = 0; j < 4; j++) acc[i][j] = (v4f){0.f, 0.f, 0.f, 0.f};

    for (int kb = 0; kb < KPAD / 32; ++kb) {
        __syncthreads();
#pragma unroll
        for (int t = 0; t < 2; t++) {
            int k = kb * 32 + aOff[t];
            k = (k > 1992) ? 1992 : k;          // stay in-bounds; Wb pad zeros the rest
            glds16(aRow[t] + k, aDst[t]);
            glds16(bSrc[t] + kb * 32, bDst[t]);
        }
        __syncthreads();

        v8s af[4], bf[4];
#pragma unroll
        for (int i = 0; i < 4; i++) {
            const int r = wm + i * 16 + lm;
            af[i] = *(const v8s*)&As[r * 32 + (quad ^ ((r >> 1) & 3)) * 8];
        }
#pragma unroll
        for (int j = 0; j < 4; j++) {
            const int r = wn + j * 16 + lm;
            bf[j] = *(const v8s*)&Bs[r * 32 + (quad ^ ((r >> 1) & 3)) * 8];
        }
#pragma unroll
        for (int i = 0; i < 4; i++)
#pragma unroll
            for (int j = 0; j < 4; j++)
                acc[i][j] = __builtin_amdgcn_mfma_f32_16x16x32_bf16(af[i], bf[j], acc[i][j], 0, 0, 0);
    }

#pragma unroll
    for (int i = 0; i < 4; i++) {
#pragma unroll
        for (int r = 0; r < 4; r++) {
            const int row = m_base + wm + i * 16 + quad * 4 + r;
            const int ty = i_ty[row], la = i_la[row], op = i_op[row];
            const int di = i_in[row], doo = i_ou[row];
            const float* pte = te + (size_t)ty * HDIM;
            const float* ple = le + (size_t)la * HDIM;
            const float* poe = oe + (size_t)op * HDIM;
            const float* pie = ie + (size_t)di * HDIM;
            const float* pou = ooe + (size_t)doo * HDIM;
            u16* orow = Xb + (size_t)row * HDIM;
#pragma unroll
            for (int j = 0; j < 4; j++) {
                const int col = n_base + wn + j * 16 + lm;
                float v = acc[i][j][r] + pb[col] + pte[col] + ple[col] + poe[col] + pie[col] + pou[col];
                orow[col] = f2b(v);
            }
        }
    }
}

// ---------------- K1f: fallback fused-conversion GEMM1 (round-2, used if ws small) ------
__global__ __launch_bounds__(256, 3) void gemm1_fused(
    const float* __restrict__ A, const u16* __restrict__ Wb,
    const float* __restrict__ pb,
    const int* __restrict__ i_ty, const int* __restrict__ i_la,
    const int* __restrict__ i_op, const int* __restrict__ i_in, const int* __restrict__ i_ou,
    const float* __restrict__ te, const float* __restrict__ le, const float* __restrict__ oe,
    const float* __restrict__ ie, const float* __restrict__ ooe,
    u16* __restrict__ Xb)
{
    __shared__ __align__(16) float Asf[128 * 32];
    __shared__ __align__(16) u16  Bs[128 * 32];

    const int bid = blockIdx.x;
    const int slot = bid >> 3;
    const int mt = (bid & 7) * 32 + slot / 6;
    const int nt = slot % 6;
    const int m_base = mt * 128, n_base = nt * 128;

    const int tid = threadIdx.x;
    const int w = tid >> 6, lane = tid & 63;
    const int lm = lane & 15, quad = lane >> 4;
    const int wm = (w >> 1) * 64, wn = (w & 1) * 64;

    const float* aRowBase[4]; int aChunkOff[4]; float* aDst[4];
#pragma unroll
    for (int t = 0; t < 4; t++) {
        const int rl = w * 32 + t * 8 + (lane >> 3);
        const int c16 = (lane & 7) ^ (rl & 7);
        aRowBase[t] = A + (size_t)(m_base + rl) * KDIM;
        aChunkOff[t] = c16 * 4;
        aDst[t] = &Asf[(w * 32 + t * 8) * 32];
    }
    const u16* bSrc[2]; u16* bDst[2];
#pragma unroll
    for (int t = 0; t < 2; t++) {
        const int rl = w * 32 + t * 16 + (lane >> 2);
        const int c = (lane & 3) ^ ((rl >> 1) & 3);
        bSrc[t] = Wb + (size_t)(n_base + rl) * KPAD + c * 8;
        bDst[t] = &Bs[(w * 32 + t * 16) * 32];
    }

    v4f acc[4][4];
#pragma unroll
    for (int i = 0; i < 4; i++)
#pragma unroll
        for (int j = 0; j < 4; j++) acc[i][j] = (v4f){0.f, 0.f, 0.f, 0.f};

    for (int kb = 0; kb < KPAD / 32; ++kb) {
        __syncthreads();
#pragma unroll
        for (int t = 0; t < 4; t++) {
            int k = kb * 32 + aChunkOff[t];
            k = (k > 1996) ? 1996 : k;
            glds16(aRowBase[t] + k, aDst[t]);
        }
#pragma unroll
        for (int t = 0; t < 2; t++)
            glds16(bSrc[t] + kb * 32, bDst[t]);
        __syncthreads();

        v8s af[4], bf[4];
#pragma unroll
        for (int i = 0; i < 4; i++) {
            const int r = wm + i * 16 + lm;
            const int sw = r & 7;
            const float4 lo = *(const float4*)&Asf[r * 32 + (((2 * quad)     ^ sw) << 2)];
            const float4 hi = *(const float4*)&Asf[r * 32 + (((2 * quad + 1) ^ sw) << 2)];
            int4 p;
            p.x = (int)pk2(lo.x, lo.y); p.y = (int)pk2(lo.z, lo.w);
            p.z = (int)pk2(hi.x, hi.y); p.w = (int)pk2(hi.z, hi.w);
            af[i] = __builtin_bit_cast(v8s, p);
        }
#pragma unroll
        for (int j = 0; j < 4; j++) {
            const int r = wn + j * 16 + lm;
            bf[j] = *(const v8s*)&Bs[r * 32 + (quad ^ ((r >> 1) & 3)) * 8];
        }
#pragma unroll
        for (int i = 0; i < 4; i++)
#pragma unroll
            for (int j = 0; j < 4; j++)
                acc[i][j] = __builtin_amdgcn_mfma_f32_16x16x32_bf16(af[i], bf[j], acc[i][j], 0, 0, 0);
    }

#pragma unroll
    for (int i = 0; i < 4; i++) {
#pragma unroll
        for (int r = 0; r < 4; r++) {
            const int row = m_base + wm + i * 16 + quad * 4 + r;
            const int ty = i_ty[row], la = i_la[row], op = i_op[row];
            const int di = i_in[row], doo = i_ou[row];
            const float* pte = te + (size_t)ty * HDIM;
            const float* ple = le + (size_t)la * HDIM;
            const float* poe = oe + (size_t)op * HDIM;
            const float* pie = ie + (size_t)di * HDIM;
            const float* pou = ooe + (size_t)doo * HDIM;
            u16* orow = Xb + (size_t)row * HDIM;
#pragma unroll
            for (int j = 0; j < 4; j++) {
                const int col = n_base + wn + j * 16 + lm;
                float v = acc[i][j][r] + pb[col] + pte[col] + ple[col] + poe[col] + pie[col] + pou[col];
                orow[col] = f2b(v);
            }
        }
    }
}

// ---------------- K2: GEMM2  y[m,g] = xb[m,:] . NWb[g,:] + neg_b ------------------------
__global__ __launch_bounds__(256, 4) void gemm2(
    const u16* __restrict__ Xb, const u16* __restrict__ NWb,
    const float* __restrict__ nb, u16* __restrict__ Yb)
{
    __shared__ __align__(16) u16 As[128 * 32];
    __shared__ __align__(16) u16 Bs[128 * 32];

    const int bid = blockIdx.x;
    const int slot = bid >> 3;
    const int mt = (bid & 7) * 32 + slot / 6;
    const int nt = slot % 6;
    const int m_base = mt * 128, n_base = nt * 128;

    const int tid = threadIdx.x;
    const int w = tid >> 6, lane = tid & 63;
    const int lm = lane & 15, quad = lane >> 4;
    const int wm = (w >> 1) * 64, wn = (w & 1) * 64;

    const u16* aSrc[2]; u16* aDst[2];
    const u16* bSrc[2]; u16* bDst[2];
#pragma unroll
    for (int t = 0; t < 2; t++) {
        const int rl = w * 32 + t * 16 + (lane >> 2);
        const int c = (lane & 3) ^ ((rl >> 1) & 3);
        aSrc[t] = Xb  + (size_t)(m_base + rl) * HDIM + c * 8;
        aDst[t] = &As[(w * 32 + t * 16) * 32];
        bSrc[t] = NWb + (size_t)(n_base + rl) * HDIM + c * 8;
        bDst[t] = &Bs[(w * 32 + t * 16) * 32];
    }

    v4f acc[4][4];
#pragma unroll
    for (int i = 0; i < 4; i++)
#pragma unroll
        for (int j = 0; j < 4; j++) acc[i][j] = (v4f){0.f, 0.f, 0.f, 0.f};

    for (int kb = 0; kb < HDIM / 32; ++kb) {
        __syncthreads();
#pragma unroll
        for (int t = 0; t < 2; t++) {
            glds16(aSrc[t] + kb * 32, aDst[t]);
            glds16(bSrc[t] + kb * 32, bDst[t]);
        }
        __syncthreads();

        v8s af[4], bf[4];
#pragma unroll
        for (int i = 0; i < 4; i++) {
            const int r = wm + i * 16 + lm;
            af[i] = *(const v8s*)&As[r * 32 + (quad ^ ((r >> 1) & 3)) * 8];
        }
#pragma unroll
        for (int j = 0; j < 4; j++) {
            const int r = wn + j * 16 + lm;
            bf[j] = *(const v8s*)&Bs[r * 32 + (quad ^ ((r >> 1) & 3)) * 8];
        }
#pragma unroll
        for (int i = 0; i < 4; i++)
#pragma unroll
            for (int j = 0; j < 4; j++)
                acc[i][j] = __builtin_amdgcn_mfma_f32_16x16x32_bf16(af[i], bf[j], acc[i][j], 0, 0, 0);
    }

#pragma unroll
    for (int i = 0; i < 4; i++) {
#pragma unroll
        for (int r = 0; r < 4; r++) {
            const int row = m_base + wm + i * 16 + quad * 4 + r;
            u16* orow = Yb + (size_t)row * HDIM;
#pragma unroll
            for (int j = 0; j < 4; j++) {
                const int col = n_base + wn + j * 16 + lm;
                orow[col] = f2b(acc[i][j][r] + nb[col]);
            }
        }
    }
}

// ---------------- K3: select (negs) + LayerNorm, one wave per row -----------------------
__global__ __launch_bounds__(256) void ln_k(
    const u16* __restrict__ Xb, const u16* __restrict__ Yb,
    const int* __restrict__ negs,
    const float* __restrict__ g, const float* __restrict__ b,
    float* __restrict__ out)
{
    const int w = threadIdx.x >> 6, lane = threadIdx.x & 63;
    const int row = blockIdx.x * 4 + w;
    const u16* src = ((negs[row] == 1) ? Yb : Xb) + (size_t)row * HDIM;

    float v[12];
    float s = 0.f, ss = 0.f;
#pragma unroll
    for (int p = 0; p < 3; p++) {
        uint2 u = *(const uint2*)(src + (p * 64 + lane) * 4);
        float f0 = __builtin_bit_cast(float, u.x << 16);
        float f1 = __builtin_bit_cast(float, u.x & 0xFFFF0000u);
        float f2 = __builtin_bit_cast(float, u.y << 16);
        float f3 = __builtin_bit_cast(float, u.y & 0xFFFF0000u);
        v[p * 4 + 0] = f0; v[p * 4 + 1] = f1; v[p * 4 + 2] = f2; v[p * 4 + 3] = f3;
        s += f0 + f1 + f2 + f3;
        ss += f0 * f0 + f1 * f1 + f2 * f2 + f3 * f3;
    }
#pragma unroll
    for (int off = 1; off < 64; off <<= 1) {
        s += __shfl_xor(s, off);
        ss += __shfl_xor(ss, off);
    }
    const float mean = s * (1.f / (float)HDIM);
    const float var = ss * (1.f / (float)HDIM) - mean * mean;
    const float rs = rsqrtf(var + 1e-12f);

    float* orow = out + (size_t)row * HDIM;
#pragma unroll
    for (int p = 0; p < 3; p++) {
        const int c0 = (p * 64 + lane) * 4;
        float4 gg = *(const float4*)(g + c0);
        float4 bb = *(const float4*)(b + c0);
        float4 o;
        o.x = (v[p * 4 + 0] - mean) * rs * gg.x + bb.x;
        o.y = (v[p * 4 + 1] - mean) * rs * gg.y + bb.y;
        o.z = (v[p * 4 + 2] - mean) * rs * gg.z + bb.z;
        o.w = (v[p * 4 + 3] - mean) * rs * gg.w + bb.w;
        *(float4*)(orow + c0) = o;
    }
}

extern "C" void kernel_launch(void* const* d_in, const int* in_sizes, int n_in,
                              void* d_out, int out_size, void* d_ws, size_t ws_size,
                              hipStream_t stream) {
    (void)in_sizes; (void)n_in; (void)out_size;
    const float* A   = (const float*)d_in[0];
    const int* i_ty  = (const int*)d_in[1];
    const int* i_la  = (const int*)d_in[2];
    const int* i_op  = (const int*)d_in[3];
    const int* i_in  = (const int*)d_in[4];
    const int* i_ou  = (const int*)d_in[5];
    const int* negs  = (const int*)d_in[6];
    const float* te  = (const float*)d_in[7];
    const float* le  = (const float*)d_in[8];
    const float* oe  = (const float*)d_in[9];
    const float* ie  = (const float*)d_in[10];
    const float* ooe = (const float*)d_in[11];
    const float* pw  = (const float*)d_in[12];
    const float* pb  = (const float*)d_in[13];
    const float* nw  = (const float*)d_in[14];
    const float* nb  = (const float*)d_in[15];
    const float* lng = (const float*)d_in[16];
    const float* lnb = (const float*)d_in[17];
    float* out = (float*)d_out;

    // workspace layout
    char* ws = (char*)d_ws;
    const size_t oWb  = 0;
    const size_t oNWb = oWb  + (size_t)768 * KPAD * 2;        //  3,096,576
    const size_t oXb  = oNWb + (size_t)768 * HDIM * 2;        //  1,179,648
    const size_t oYb  = oXb  + (size_t)MTOT * HDIM * 2;       // 50,331,648
    const size_t oAb  = oYb  + (size_t)MTOT * HDIM * 2;       // 50,331,648
    const size_t need = oAb  + (size_t)MTOT * KDIM * 2;       // +131,072,000 = 236,011,520
    u16* Wb  = (u16*)(ws + oWb);
    u16* NWb = (u16*)(ws + oNWb);
    u16* Xb  = (u16*)(ws + oXb);
    u16* Yb  = (u16*)(ws + oYb);
    u16* Ab  = (u16*)(ws + oAb);

    cvt_weights<<<768, 256, 0, stream>>>(pw, nw, Wb, NWb);
    if (ws_size >= need) {
        cvt_a<<<4096, 256, 0, stream>>>(A, Ab);
        gemm1<<<1536, 256, 0, stream>>>(Ab, Wb, pb, i_ty, i_la, i_op, i_in, i_ou,
                                        te, le, oe, ie, ooe, Xb);
    } else {
        gemm1_fused<<<1536, 256, 0, stream>>>(A, Wb, pb, i_ty, i_la, i_op, i_in, i_ou,
                                              te, le, oe, ie, ooe, Xb);
    }
    gemm2<<<1536, 256, 0, stream>>>(Xb, NWb, nb, Yb);
    ln_k<<<8192, 256, 0, stream>>>(Xb, Yb, negs, lng, lnb, out);
}